// Round 6
// baseline (291.570 us; speedup 1.0000x reference)
//
#include <hip/hip_runtime.h>
#include <hip/hip_cooperative_groups.h>
#include <math.h>

namespace cg = cooperative_groups;

// Problem constants (fixed by the reference)
#define N_NODES 50000
#define N_EDGES 800000
#define FN_DIM 16
#define HD 64
#define T_CAP 1024     // |need1| measured 355
#define T2_CAP 64      // |need2| measured ~17
#define MAXDEG 128     // in-degree cap (Poisson(16))
#define NBLK 256
#define NTHR 256

struct KP {
  const float *x; const int *ei;
  const float *Wn,*bn,*gn,*betan;
  const float *Wc1,*bc1,*Wc2,*bc2;
  const float *Wg,*att_s,*att_d,*bg;
  const float *Wq1,*bq1,*gq,*betaq,*Wq2,*bq2;
  const float *Wv1,*bv1,*gv,*betav,*Wv2,*bv2;
  float *out;
  float *hB,*hA,*pvec;
  int *need1,*need2,*deg1,*deg2,*deg3,*cnt,*idx1,*idx2,*list1,*list2,*eb1,*eb2,*eb3;
  int zero4;
};

__device__ __forceinline__ float wsum64(float v) {
    #pragma unroll
    for (int o = 1; o < 64; o <<= 1) v += __shfl_xor(v, o);
    return v;
}
__device__ __forceinline__ float lrelu02(float v) { return v > 0.f ? v : 0.2f * v; }

__global__ __launch_bounds__(NTHR, 1) void k_all(KP p) {
    cg::grid_group gg = cg::this_grid();
    __shared__ float wA[HD * HD];      // Wc1a / Wq1
    __shared__ float wB[HD * HD];      // Wc1b / Wv1
    __shared__ float wC[HD * HD];      // Wc2  / Wq2
    __shared__ float wG[HD * HD];      // Wg
    __shared__ float wN[FN_DIM * HD];  // Wn (layer 0)
    __shared__ float sv[8 * HD];
    __shared__ float redA[4][HD], redH[4][HD];
    __shared__ float sM[4], sW[4], sHbar[HD];

    const int tid = threadIdx.x, lane = tid & 63, wv = tid >> 6;
    const int bid = blockIdx.x;
    const int gt = bid * NTHR + tid, gsz = NBLK * NTHR;

    // ---- P0: zero flag/counter zone
    int4* zb = (int4*)p.need1;
    for (int i = gt; i < p.zero4; i += gsz) zb[i] = make_int4(0, 0, 0, 0);
    gg.sync();

    // ---- P1: mark2 (sources of edges into node 0) + seed node 0
    const int4* d4p = (const int4*)(p.ei + N_EDGES);
    const int4* s4p = (const int4*)p.ei;
    if (gt == 0) { p.need1[0] = 1; p.need2[0] = 1; }
    for (int i = gt; i < N_EDGES / 4; i += gsz) {
        int4 d4 = d4p[i], s4 = s4p[i];
        if (d4.x == 0) { p.need2[s4.x] = 1; p.need1[s4.x] = 1; }
        if (d4.y == 0) { p.need2[s4.y] = 1; p.need1[s4.y] = 1; }
        if (d4.z == 0) { p.need2[s4.z] = 1; p.need1[s4.z] = 1; }
        if (d4.w == 0) { p.need2[s4.w] = 1; p.need1[s4.w] = 1; }
    }
    gg.sync();

    // ---- P2: mark1 (sources of edges into need2)
    for (int i = gt; i < N_EDGES / 4; i += gsz) {
        int4 d4 = d4p[i], s4 = s4p[i];
        if (p.need2[d4.x]) p.need1[s4.x] = 1;
        if (p.need2[d4.y]) p.need1[s4.y] = 1;
        if (p.need2[d4.z]) p.need1[s4.z] = 1;
        if (p.need2[d4.w]) p.need1[s4.w] = 1;
    }
    gg.sync();

    // ---- P3: compact lists + idx maps; blocks 0..5 compute ps/pd = Wg^T att vecs
    for (int i = gt; i < N_NODES; i += gsz) {
        if (p.need1[i]) { int q = atomicAdd(&p.cnt[0], 1); if (q < T_CAP)  { p.list1[q] = i; p.idx1[i] = q; } }
        if (p.need2[i]) { int q = atomicAdd(&p.cnt[1], 1); if (q < T2_CAP) { p.list2[q] = i; p.idx2[i] = q; } }
    }
    if (bid < 6 && wv == 0) {
        int l = bid >> 1, which = bid & 1;
        const float* att = (which ? p.att_d : p.att_s) + l * HD;
        float av = att[lane];
        const float* wg = p.Wg + l * HD * HD + lane * HD;
        float acc = 0.f;
        #pragma unroll 8
        for (int c = 0; c < HD; c++) acc += wg[c] * __shfl(av, c);
        p.pvec[l * 2 * HD + which * HD + lane] = acc;
    }
    gg.sync();

    // ---- P4: bucket edges per target slot
    for (int i = gt; i < N_EDGES / 4; i += gsz) {
        int4 d4 = d4p[i], s4 = s4p[i];
        int dd[4] = {d4.x, d4.y, d4.z, d4.w};
        int ss[4] = {s4.x, s4.y, s4.z, s4.w};
        #pragma unroll
        for (int c = 0; c < 4; c++) {
            int d = dd[c], s = ss[c];
            if (p.need1[d]) {
                int t = p.idx1[d];
                if ((unsigned)t < T_CAP) { int q = atomicAdd(&p.deg1[t], 1); if (q < MAXDEG) p.eb1[t * MAXDEG + q] = s; }
            }
            if (p.need2[d]) {
                int t = p.idx2[d];
                if ((unsigned)t < T2_CAP) { int q = atomicAdd(&p.deg2[t], 1); if (q < MAXDEG) p.eb2[t * MAXDEG + q] = s; }
            }
            if (d == 0) { int q = atomicAdd(p.deg3, 1); if (q < MAXDEG) p.eb3[q] = s; }
        }
    }
    gg.sync();

    // ---- layers (shared code, runtime l)
    for (int l = 0; l < 3; l++) {
        const float* Wc1l = p.Wc1 + l * 2 * HD * HD;
        for (int i = tid; i < HD * HD / 4; i += NTHR) {
            ((float4*)wA)[i] = ((const float4*)Wc1l)[i];
            ((float4*)wB)[i] = ((const float4*)(Wc1l + HD * HD))[i];
            ((float4*)wC)[i] = ((const float4*)(p.Wc2 + l * HD * HD))[i];
            ((float4*)wG)[i] = ((const float4*)(p.Wg + l * HD * HD))[i];
        }
        if (l == 0)
            for (int i = tid; i < FN_DIM * HD / 4; i += NTHR)
                ((float4*)wN)[i] = ((const float4*)p.Wn)[i];
        if (tid < HD) {
            sv[0 * HD + tid] = p.bc1[l * HD + tid];
            sv[1 * HD + tid] = p.bc2[l * HD + tid];
            sv[2 * HD + tid] = p.bg[l * HD + tid];
            sv[3 * HD + tid] = p.pvec[l * 2 * HD + tid];        // ps
            sv[4 * HD + tid] = p.pvec[l * 2 * HD + HD + tid];   // pd
            sv[5 * HD + tid] = p.bn[tid];
            sv[6 * HD + tid] = p.gn[tid];
            sv[7 * HD + tid] = p.betan[tid];
        }
        __syncthreads();

        int ntgt = (l == 0) ? min(p.cnt[0], T_CAP) : (l == 1) ? min(p.cnt[1], T2_CAP) : 1;
        const int* tl  = (l == 0) ? p.list1 : p.list2;
        const int* ebp = (l == 0) ? p.eb1 : (l == 1) ? p.eb2 : p.eb3;
        const int* dgp = (l == 0) ? p.deg1 : (l == 1) ? p.deg2 : p.deg3;
        const float* hin = (l == 1) ? p.hB : p.hA;   // l==2 -> hA; l==0 unused
        float* hout = (l == 0) ? p.hB : p.hA;

        for (int w = bid; w < ntgt; w += NBLK) {
            int t = (l == 2) ? 0 : tl[w];
            int dg = dgp[(l == 2) ? 0 : w]; if (dg > MAXDEG) dg = MAXDEG;
            const int* row = ebp + (size_t)((l == 2) ? 0 : w) * MAXDEG;

            // target feature
            float hval;
            if (l == 0) {
                float xv = p.x[t * FN_DIM + (lane & 15)];
                float acc = sv[5 * HD + lane];
                #pragma unroll
                for (int k = 0; k < FN_DIM; k++) acc += __shfl(xv, k) * wN[k * HD + lane];
                float vv = fmaxf(acc, 0.f);
                float mu = wsum64(vv) * (1.f / 64.f);
                float d2 = vv - mu;
                float var = wsum64(d2 * d2) * (1.f / 64.f);
                hval = d2 * rsqrtf(var + 1e-5f) * sv[6 * HD + lane] + sv[7 * HD + lane];
            } else hval = hin[(size_t)t * HD + lane];

            float a_st = wsum64(hval * sv[3 * HD + lane]);
            float a_dt = wsum64(hval * sv[4 * HD + lane]);
            float es = lrelu02(a_st + a_dt);           // GAT self-loop logit

            // u = bc1 + Wc1a.h_t  (LDS weights)
            float uval = sv[0 * HD + lane];
            #pragma unroll 8
            for (int k = 0; k < HD; k++) uval += __shfl(hval, k) * wA[k * HD + lane];

            // edge phase: 1 edge per wave per pass, online softmax in registers
            float aggw = -INFINITY, mrun = -INFINITY, wpart = 0.f, hw = 0.f;
            for (int j = wv; j < dg; j += 4) {
                int s = row[j];
                float hs;
                if (l == 0) {
                    float xv = p.x[s * FN_DIM + (lane & 15)];
                    float acc = sv[5 * HD + lane];
                    #pragma unroll
                    for (int k = 0; k < FN_DIM; k++) acc += __shfl(xv, k) * wN[k * HD + lane];
                    float vv = fmaxf(acc, 0.f);
                    float mu = wsum64(vv) * (1.f / 64.f);
                    float d2 = vv - mu;
                    float var = wsum64(d2 * d2) * (1.f / 64.f);
                    hs = d2 * rsqrtf(var + 1e-5f) * sv[6 * HD + lane] + sv[7 * HD + lane];
                } else hs = hin[(size_t)s * HD + lane];

                float logit = lrelu02(wsum64(hs * sv[3 * HD + lane]) + a_dt);
                float v = 0.f;
                #pragma unroll 8
                for (int k = 0; k < HD; k++) v += __shfl(hs, k) * wB[k * HD + lane];
                float hid = fmaxf(uval + v, 0.f);
                float m = sv[1 * HD + lane];
                #pragma unroll 8
                for (int k = 0; k < HD; k++) m += __shfl(hid, k) * wC[k * HD + lane];
                aggw = fmaxf(aggw, m);
                if (logit > mrun) { float sc = expf(mrun - logit); hw *= sc; wpart *= sc; mrun = logit; }
                float we = expf(logit - mrun);
                hw += we * hs; wpart += we;
            }
            redA[wv][lane] = aggw;
            redH[wv][lane] = hw;
            if (lane == 0) { sM[wv] = mrun; sW[wv] = wpart; }
            __syncthreads();

            if (wv == 0) {
                float M = es;
                #pragma unroll
                for (int q = 0; q < 4; q++) M = fmaxf(M, sM[q]);
                float den = expf(es - M);
                float num = den * hval;
                #pragma unroll
                for (int q = 0; q < 4; q++) {
                    float sc = (sM[q] == -INFINITY) ? 0.f : expf(sM[q] - M);
                    num += sc * redH[q][lane];
                    den += sc * sW[q];
                }
                float hbar = num / den;
                float att = sv[2 * HD + lane];
                #pragma unroll 8
                for (int k = 0; k < HD; k++) att += __shfl(hbar, k) * wG[k * HD + lane];
                float agg = fmaxf(fmaxf(redA[0][lane], redA[1][lane]),
                                  fmaxf(redA[2][lane], redA[3][lane]));
                if (dg == 0) agg = 0.f;   // PyG scatter-max: empty segment -> 0
                float hv = fmaxf(hval + agg + att, 0.f);
                if (l < 2) hout[(size_t)t * HD + lane] = hv;
                else sHbar[lane] = hv;
            }
            __syncthreads();
        }
        if (l < 2) gg.sync();
    }

    // ---- heads on block 0 (t = node 0 state in sHbar)
    if (bid == 0) {
        for (int i = tid; i < HD * HD / 4; i += NTHR) {
            ((float4*)wA)[i] = ((const float4*)p.Wq1)[i];
            ((float4*)wB)[i] = ((const float4*)p.Wv1)[i];
        }
        for (int i = tid; i < HD * 32 / 4; i += NTHR)
            ((float4*)wC)[i] = ((const float4*)p.Wq2)[i];
        if (tid < HD) {
            sv[0 * HD + tid] = p.bq1[tid]; sv[1 * HD + tid] = p.gq[tid];
            sv[2 * HD + tid] = p.betaq[tid];
            sv[3 * HD + tid] = p.bv1[tid]; sv[4 * HD + tid] = p.gv[tid];
            sv[5 * HD + tid] = p.betav[tid];
            sv[6 * HD + tid] = p.Wv2[tid];
        }
        if (tid < 32) sv[7 * HD + tid] = p.bq2[tid];
        __syncthreads();
        float hvv = sHbar[lane];
        if (wv == 0) {            // q head
            float acc = sv[0 * HD + lane];
            #pragma unroll 8
            for (int k = 0; k < HD; k++) acc += __shfl(hvv, k) * wA[k * HD + lane];
            float r = fmaxf(acc, 0.f);
            float mu = wsum64(r) * (1.f / 64.f);
            float d2 = r - mu;
            float var = wsum64(d2 * d2) * (1.f / 64.f);
            float tq = d2 * rsqrtf(var + 1e-5f) * sv[1 * HD + lane] + sv[2 * HD + lane];
            int s2 = lane & 31;
            float q = sv[7 * HD + s2];
            #pragma unroll 8
            for (int k = 0; k < HD; k++) q += __shfl(tq, k) * wC[k * 32 + s2];
            if (lane < 32) p.out[lane] = q;
        } else if (wv == 1) {     // value head
            float accv = sv[3 * HD + lane];
            #pragma unroll 8
            for (int k = 0; k < HD; k++) accv += __shfl(hvv, k) * wB[k * HD + lane];
            float rv = fmaxf(accv, 0.f);
            float muv = wsum64(rv) * (1.f / 64.f);
            float dv = rv - muv;
            float varv = wsum64(dv * dv) * (1.f / 64.f);
            float tv = dv * rsqrtf(varv + 1e-5f) * sv[4 * HD + lane] + sv[5 * HD + lane];
            float vs = wsum64(tv * sv[6 * HD + lane]);
            if (lane == 0) p.out[32] = vs + p.bv2[0];
        }
    }
}

extern "C" void kernel_launch(void* const* d_in, const int* in_sizes, int n_in,
                              void* d_out, int out_size, void* d_ws, size_t ws_size,
                              hipStream_t stream) {
    KP p;
    p.x      = (const float*)d_in[0];
    p.ei     = (const int*)d_in[1];
    // d_in[2] edge_attr and d_in[7..10] (edge encoder) are dead code in the reference
    p.Wn     = (const float*)d_in[3];
    p.bn     = (const float*)d_in[4];
    p.gn     = (const float*)d_in[5];
    p.betan  = (const float*)d_in[6];
    p.Wc1    = (const float*)d_in[11];
    p.bc1    = (const float*)d_in[12];
    p.Wc2    = (const float*)d_in[13];
    p.bc2    = (const float*)d_in[14];
    p.Wg     = (const float*)d_in[15];
    p.att_s  = (const float*)d_in[16];
    p.att_d  = (const float*)d_in[17];
    p.bg     = (const float*)d_in[18];
    p.Wq1    = (const float*)d_in[19];
    p.bq1    = (const float*)d_in[20];
    p.gq     = (const float*)d_in[21];
    p.betaq  = (const float*)d_in[22];
    p.Wq2    = (const float*)d_in[23];
    p.bq2    = (const float*)d_in[24];
    p.Wv1    = (const float*)d_in[25];
    p.bv1    = (const float*)d_in[26];
    p.gv     = (const float*)d_in[27];
    p.betav  = (const float*)d_in[28];
    p.Wv2    = (const float*)d_in[29];
    p.bv2    = (const float*)d_in[30];
    p.out    = (float*)d_out;

    // ---- workspace carve (~27 MB)
    p.hB    = (float*)d_ws;                         // N*HD
    p.hA    = p.hB + (size_t)N_NODES * HD;          // N*HD
    p.need1 = (int*)(p.hA + (size_t)N_NODES * HD);  // zero-zone start
    p.need2 = p.need1 + N_NODES;
    p.deg1  = p.need2 + N_NODES;                    // T_CAP
    p.deg2  = p.deg1 + T_CAP;                       // T2_CAP
    p.deg3  = p.deg2 + T2_CAP;                      // 4
    p.cnt   = p.deg3 + 4;                           // 8   (zero-zone end)
    p.idx1  = p.cnt + 8;                            // N
    p.idx2  = p.idx1 + N_NODES;                     // N
    p.list1 = p.idx2 + N_NODES;                     // T_CAP
    p.list2 = p.list1 + T_CAP;                      // T2_CAP
    p.eb1   = p.list2 + T2_CAP;                     // T_CAP*MAXDEG
    p.eb2   = p.eb1 + (size_t)T_CAP * MAXDEG;       // T2_CAP*MAXDEG
    p.eb3   = p.eb2 + (size_t)T2_CAP * MAXDEG;      // MAXDEG
    p.pvec  = (float*)(p.eb3 + MAXDEG);             // 3*128
    p.zero4 = (2 * N_NODES + T_CAP + T2_CAP + 12) / 4;   // 25275 int4

    void* kargs[] = { (void*)&p };
    hipLaunchCooperativeKernel((void*)k_all, dim3(NBLK), dim3(NTHR), kargs, 0, stream);
}

// Round 7
// 97.612 us; speedup vs baseline: 2.9870x; 2.9870x over previous
//
#include <hip/hip_runtime.h>
#include <math.h>

// Problem constants (fixed by the reference)
#define N_NODES 50000
#define N_EDGES 800000
#define FN_DIM 16
#define HD 64
#define T_CAP 8192     // cap on |need1| (expected ~290)  = layer-0 targets
#define T2_CAP 512     // cap on |need2| (expected ~17)   = layer-1 targets
#define MAXDEG 128     // cap on in-degree (Poisson(16))

// ---------- wave-64 helpers ----------
__device__ __forceinline__ float wsum64(float v) {
    #pragma unroll
    for (int o = 1; o < 64; o <<= 1) v += __shfl_xor(v, o);
    return v;
}
__device__ __forceinline__ float wmax64(float v) {
    #pragma unroll
    for (int o = 1; o < 64; o <<= 1) v = fmaxf(v, __shfl_xor(v, o));
    return v;
}
__device__ __forceinline__ float lrelu02(float v) { return v > 0.f ? v : 0.2f * v; }

// ---------- zero the flag/counter zone (replaces the 42us rocclr fill) ----------
__global__ void k_zero(int4* __restrict__ p, int n4) {
    int i = blockIdx.x * blockDim.x + threadIdx.x;
    if (i < n4) p[i] = make_int4(0, 0, 0, 0);
}

// ---------- discovery ----------
__global__ void k_mark2(const int* __restrict__ ei, int* need1, int* need2) {
    int e = blockIdx.x * blockDim.x + threadIdx.x;
    if (e == 0) { need1[0] = 1; need2[0] = 1; }
    if (e >= N_EDGES) return;
    if (ei[N_EDGES + e] == 0) { int s = ei[e]; need2[s] = 1; need1[s] = 1; }
}
__global__ void k_mark1(const int* __restrict__ ei, const int* __restrict__ need2, int* need1) {
    int e = blockIdx.x * blockDim.x + threadIdx.x;
    if (e >= N_EDGES) return;
    if (need2[ei[N_EDGES + e]]) need1[ei[e]] = 1;
}
__global__ void k_compact(const int* __restrict__ need1, const int* __restrict__ need2,
                          int* list1, int* list2, int* idx1, int* idx2, int* cnt) {
    int i = blockIdx.x * blockDim.x + threadIdx.x;
    if (i >= N_NODES) return;
    if (need1[i]) { int p = atomicAdd(&cnt[0], 1); if (p < T_CAP)  { list1[p] = i; idx1[i] = p; } }
    if (need2[i]) { int p = atomicAdd(&cnt[1], 1); if (p < T2_CAP) { list2[p] = i; idx2[i] = p; } }
}
__global__ void k_bucket(const int* __restrict__ ei, const int* __restrict__ need1,
                         const int* __restrict__ need2,
                         const int* __restrict__ idx1, const int* __restrict__ idx2,
                         int* eb1, int* deg1, int* eb2, int* deg2, int* eb3, int* deg3) {
    int e = blockIdx.x * blockDim.x + threadIdx.x;
    if (e >= N_EDGES) return;
    int d = ei[N_EDGES + e];
    int s = ei[e];
    if (need1[d]) {
        int t = idx1[d];
        if ((unsigned)t < T_CAP) { int p = atomicAdd(&deg1[t], 1); if (p < MAXDEG) eb1[t * MAXDEG + p] = s; }
    }
    if (need2[d]) {
        int t = idx2[d];
        if ((unsigned)t < T2_CAP) { int p = atomicAdd(&deg2[t], 1); if (p < MAXDEG) eb2[t * MAXDEG + p] = s; }
    }
    if (d == 0) { int p = atomicAdd(deg3, 1); if (p < MAXDEG) eb3[p] = s; }
}

// ---------- node feature: layer 0 encodes from x, later layers load h ----------
template<int LM>
__device__ __forceinline__ float node_h(int i, int lane,
    const float* __restrict__ x, const float* __restrict__ Wn, const float* __restrict__ bn,
    const float* __restrict__ gn, const float* __restrict__ betan,
    const float* __restrict__ hin) {
    if (LM == 0) {
        float acc = bn[lane];
        #pragma unroll
        for (int k = 0; k < FN_DIM; k++) acc += x[i * FN_DIM + k] * Wn[k * HD + lane];
        float v = fmaxf(acc, 0.f);
        float mu = wsum64(v) * (1.f / 64.f);
        float d = v - mu;
        float var = wsum64(d * d) * (1.f / 64.f);
        return d * rsqrtf(var + 1e-5f) * gn[lane] + betan[lane];
    } else {
        return hin[i * HD + lane];
    }
}

// ---------- heads (wave 0 only), writes out[0..32] ----------
__device__ __forceinline__ void heads_eval(float hv, int lane,
    const float* __restrict__ Wq1, const float* __restrict__ bq1,
    const float* __restrict__ gq, const float* __restrict__ betaq,
    const float* __restrict__ Wq2, const float* __restrict__ bq2,
    const float* __restrict__ Wv1, const float* __restrict__ bv1,
    const float* __restrict__ gv, const float* __restrict__ betav,
    const float* __restrict__ Wv2, const float* __restrict__ bv2,
    float* __restrict__ out) {
    float acc = bq1[lane];
    #pragma unroll 8
    for (int k = 0; k < 64; k++) acc += __shfl(hv, k) * Wq1[k * 64 + lane];
    float r = fmaxf(acc, 0.f);
    float mu = wsum64(r) * (1.f / 64.f);
    float d = r - mu;
    float var = wsum64(d * d) * (1.f / 64.f);
    float tq = d * rsqrtf(var + 1e-5f) * gq[lane] + betaq[lane];
    float accv = bv1[lane];
    #pragma unroll 8
    for (int k = 0; k < 64; k++) accv += __shfl(hv, k) * Wv1[k * 64 + lane];
    float rv = fmaxf(accv, 0.f);
    float muv = wsum64(rv) * (1.f / 64.f);
    float dv = rv - muv;
    float varv = wsum64(dv * dv) * (1.f / 64.f);
    float tv = dv * rsqrtf(varv + 1e-5f) * gv[lane] + betav[lane];
    int s = lane & 31;
    float q = bq2[s];
    #pragma unroll 8
    for (int k = 0; k < 64; k++) q += __shfl(tq, k) * Wq2[k * 32 + s];
    if (lane < 32) out[lane] = q;
    float vsum = wsum64(tv * Wv2[lane]);
    if (lane == 0) out[32] = vsum + bv2[0];
}

// ---------- fully fused layer: block per target, 4 waves edge-parallel ----------
// EdgeConv: m = Wc2.relu(Wc1a.h_t + Wc1b.h_s + bc1) + bc2, segment-max
// GAT: softmax over in-edges + self-loop of lrelu(a_s[src]+a_d[t]), weighted sum of xg
// out: h' = relu(h_t + agg + att)
template<int LM>
__global__ __launch_bounds__(256) void k_layer(
    const float* __restrict__ x, const float* __restrict__ Wn, const float* __restrict__ bn,
    const float* __restrict__ gn, const float* __restrict__ betan,
    const float* __restrict__ hin,
    const float* __restrict__ Wc1, const float* __restrict__ bc1,
    const float* __restrict__ Wc2, const float* __restrict__ bc2,
    const float* __restrict__ Wg, const float* __restrict__ atts, const float* __restrict__ attd,
    const float* __restrict__ bgv,
    const int* __restrict__ tlist, const int* __restrict__ cntp, int tcap,
    const int* __restrict__ eb, const int* __restrict__ deg,
    float* __restrict__ hout,
    const float* __restrict__ Wq1, const float* __restrict__ bq1,
    const float* __restrict__ gq, const float* __restrict__ betaq,
    const float* __restrict__ Wq2, const float* __restrict__ bq2,
    const float* __restrict__ Wv1, const float* __restrict__ bv1,
    const float* __restrict__ gv, const float* __restrict__ betav,
    const float* __restrict__ Wv2, const float* __restrict__ bv2)
{
    __shared__ float ht[64], ut[64], xgt[64];
    __shared__ float scr[4][4][64];     // per-wave 4-edge vector scratch
    __shared__ float xgc[MAXDEG][64];   // per-edge xg cache
    __shared__ float ec[MAXDEG];        // per-edge attention logit
    __shared__ float redA[4][64], redB[4][64];
    __shared__ float sws[4];
    __shared__ float sA[2];             // a_s[t], a_d[t]
    __shared__ float sEm;

    int lane = threadIdx.x & 63;
    int wv = threadIdx.x >> 6;
    int ntgt = (LM == 2) ? 1 : min(cntp[0], tcap);

    for (int w = blockIdx.x; w < ntgt; w += gridDim.x) {
        int t = (LM == 2) ? 0 : tlist[w];
        if (wv == 0) {
            float h = node_h<LM>(t, lane, x, Wn, bn, gn, betan, hin);
            ht[lane] = h;
            float u = bc1[lane], xg = 0.f;
            #pragma unroll 4
            for (int k = 0; k < 64; k++) {
                float b = ht[k];
                u  += b * Wc1[k * 64 + lane];
                xg += b * Wg[k * 64 + lane];
            }
            ut[lane] = u; xgt[lane] = xg;
            float a_st = wsum64(xg * atts[lane]);
            float a_dt = wsum64(xg * attd[lane]);
            if (lane == 0) { sA[0] = a_st; sA[1] = a_dt; }
        }
        __syncthreads();
        int dg = deg[(LM == 2) ? 0 : w]; if (dg > MAXDEG) dg = MAXDEG;
        float a_dt = sA[1];
        float aggw = -INFINITY;

        for (int base = wv * 4; base < dg; base += 16) {
            int ne = dg - base; if (ne > 4) ne = 4;
            #pragma unroll
            for (int e = 0; e < 4; e++) {
                if (e < ne) {
                    int s = eb[w * MAXDEG + base + e];
                    scr[wv][e][lane] = node_h<LM>(s, lane, x, Wn, bn, gn, betan, hin);
                }
            }
            float v[4] = {0.f, 0.f, 0.f, 0.f};
            float g[4] = {0.f, 0.f, 0.f, 0.f};
            #pragma unroll 4
            for (int k = 0; k < 64; k++) {
                float wc = Wc1[(64 + k) * 64 + lane];
                float wg = Wg[k * 64 + lane];
                #pragma unroll
                for (int e = 0; e < 4; e++) {
                    float b = scr[wv][e][k];
                    v[e] += b * wc;
                    g[e] += b * wg;
                }
            }
            float ut_l = ut[lane];
            #pragma unroll
            for (int e = 0; e < 4; e++) scr[wv][e][lane] = fmaxf(ut_l + v[e], 0.f);
            float m[4];
            #pragma unroll
            for (int e = 0; e < 4; e++) m[e] = bc2[lane];
            #pragma unroll 4
            for (int k = 0; k < 64; k++) {
                float wc2v = Wc2[k * 64 + lane];
                #pragma unroll
                for (int e = 0; e < 4; e++) m[e] += scr[wv][e][k] * wc2v;
            }
            #pragma unroll
            for (int e = 0; e < 4; e++) {
                if (e < ne) {
                    aggw = fmaxf(aggw, m[e]);
                    int j = base + e;
                    xgc[j][lane] = g[e];
                    float a_ss = wsum64(g[e] * atts[lane]);
                    if (lane == 0) ec[j] = lrelu02(a_ss + a_dt);
                }
            }
        }
        redA[wv][lane] = aggw;
        __syncthreads();

        if (wv == 0) {
            float es = lrelu02(sA[0] + sA[1]);
            float mm = es;
            for (int j = lane; j < dg; j += 64) mm = fmaxf(mm, ec[j]);
            mm = wmax64(mm);
            if (lane == 0) sEm = mm;
        }
        __syncthreads();
        float em = sEm;
        float attv = 0.f, wsv = 0.f;
        for (int j = wv; j < dg; j += 4) {
            float wj = expf(ec[j] - em);
            attv += wj * xgc[j][lane];
            wsv += wj;
        }
        redB[wv][lane] = attv;
        if (lane == 0) sws[wv] = wsv;
        __syncthreads();

        if (wv == 0) {
            float agg = fmaxf(fmaxf(redA[0][lane], redA[1][lane]),
                              fmaxf(redA[2][lane], redA[3][lane]));
            if (dg == 0) agg = 0.f;   // PyG scatter-max: empty segment -> 0
            float es = lrelu02(sA[0] + sA[1]);
            float wself = expf(es - em);
            float att = redB[0][lane] + redB[1][lane] + redB[2][lane] + redB[3][lane]
                      + wself * xgt[lane];
            float wsum = sws[0] + sws[1] + sws[2] + sws[3] + wself;
            float hv = fmaxf(ht[lane] + agg + att / wsum + bgv[lane], 0.f);
            if (LM == 2) {
                heads_eval(hv, lane, Wq1, bq1, gq, betaq, Wq2, bq2,
                           Wv1, bv1, gv, betav, Wv2, bv2, hout);
            } else {
                hout[t * HD + lane] = hv;
            }
        }
        __syncthreads();
    }
}

extern "C" void kernel_launch(void* const* d_in, const int* in_sizes, int n_in,
                              void* d_out, int out_size, void* d_ws, size_t ws_size,
                              hipStream_t stream) {
    const float* x        = (const float*)d_in[0];
    const int*   ei       = (const int*)d_in[1];
    // d_in[2] edge_attr and d_in[7..10] (edge encoder) are dead code in the reference
    const float* Wn       = (const float*)d_in[3];
    const float* bn       = (const float*)d_in[4];
    const float* gn       = (const float*)d_in[5];
    const float* betan    = (const float*)d_in[6];
    const float* Wc1      = (const float*)d_in[11];
    const float* bc1      = (const float*)d_in[12];
    const float* Wc2      = (const float*)d_in[13];
    const float* bc2      = (const float*)d_in[14];
    const float* Wg       = (const float*)d_in[15];
    const float* att_src  = (const float*)d_in[16];
    const float* att_dst  = (const float*)d_in[17];
    const float* bg       = (const float*)d_in[18];
    const float* Wq1      = (const float*)d_in[19];
    const float* bq1      = (const float*)d_in[20];
    const float* gq       = (const float*)d_in[21];
    const float* betaq    = (const float*)d_in[22];
    const float* Wq2      = (const float*)d_in[23];
    const float* bq2      = (const float*)d_in[24];
    const float* Wv1      = (const float*)d_in[25];
    const float* bv1      = (const float*)d_in[26];
    const float* gv       = (const float*)d_in[27];
    const float* betav    = (const float*)d_in[28];
    const float* Wv2      = (const float*)d_in[29];
    const float* bv2      = (const float*)d_in[30];

    // ---- workspace layout (~31 MB)
    float* hB   = (float*)d_ws;                      // h1, N*64
    float* hA   = hB + (size_t)N_NODES * HD;         // h2, N*64
    int* need1  = (int*)(hA + (size_t)N_NODES * HD); // zero-zone start (16B aligned)
    int* need2  = need1 + N_NODES;
    int* deg1   = need2 + N_NODES;                   // T_CAP
    int* deg2   = deg1 + T_CAP;                      // T2_CAP
    int* deg3   = deg2 + T2_CAP;                     // 4
    int* cnt    = deg3 + 4;                          // 8   (zero-zone end)
    int* idx1   = cnt + 8;                           // N
    int* idx2   = idx1 + N_NODES;                    // N
    int* list1  = idx2 + N_NODES;                    // T_CAP
    int* list2  = list1 + T_CAP;                     // T2_CAP
    int* eb1    = list2 + T2_CAP;                    // T_CAP*MAXDEG
    int* eb2    = eb1 + (size_t)T_CAP * MAXDEG;      // T2_CAP*MAXDEG
    int* eb3    = eb2 + (size_t)T2_CAP * MAXDEG;     // MAXDEG
    // (pvec slot unused in this round)

    const int zero_ints = 2 * N_NODES + T_CAP + T2_CAP + 12;   // 108716, /4 exact
    const int n4 = zero_ints / 4;                    // 27179 int4
    const int EB = (N_EDGES + 255) / 256;            // 3125 blocks
    const int NB = (N_NODES + 255) / 256;            // 196 blocks

    k_zero<<<(n4 + 255) / 256, 256, 0, stream>>>((int4*)need1, n4);
    k_mark2<<<EB, 256, 0, stream>>>(ei, need1, need2);
    k_mark1<<<EB, 256, 0, stream>>>(ei, need2, need1);
    k_compact<<<NB, 256, 0, stream>>>(need1, need2, list1, list2, idx1, idx2, cnt);
    k_bucket<<<EB, 256, 0, stream>>>(ei, need1, need2, idx1, idx2,
                                     eb1, deg1, eb2, deg2, eb3, deg3);

    // layer 0: targets list1 (~355), sources encoded from x on the fly -> hB
    k_layer<0><<<512, 256, 0, stream>>>(
        x, Wn, bn, gn, betan, (const float*)nullptr,
        Wc1 + 0 * 2 * HD * HD, bc1 + 0 * HD, Wc2 + 0 * HD * HD, bc2 + 0 * HD,
        Wg + 0 * HD * HD, att_src + 0 * HD, att_dst + 0 * HD, bg + 0 * HD,
        list1, cnt + 0, T_CAP, eb1, deg1, hB,
        Wq1, bq1, gq, betaq, Wq2, bq2, Wv1, bv1, gv, betav, Wv2, bv2);

    // layer 1: targets list2 (~17), h from hB -> hA
    k_layer<1><<<64, 256, 0, stream>>>(
        x, Wn, bn, gn, betan, hB,
        Wc1 + 1 * 2 * HD * HD, bc1 + 1 * HD, Wc2 + 1 * HD * HD, bc2 + 1 * HD,
        Wg + 1 * HD * HD, att_src + 1 * HD, att_dst + 1 * HD, bg + 1 * HD,
        list2, cnt + 1, T2_CAP, eb2, deg2, hA,
        Wq1, bq1, gq, betaq, Wq2, bq2, Wv1, bv1, gv, betav, Wv2, bv2);

    // layer 2: target {0}, h from hA -> heads -> d_out
    k_layer<2><<<1, 256, 0, stream>>>(
        x, Wn, bn, gn, betan, hA,
        Wc1 + 2 * 2 * HD * HD, bc1 + 2 * HD, Wc2 + 2 * HD * HD, bc2 + 2 * HD,
        Wg + 2 * HD * HD, att_src + 2 * HD, att_dst + 2 * HD, bg + 2 * HD,
        (const int*)nullptr, cnt + 1, 1, eb3, deg3, (float*)d_out,
        Wq1, bq1, gq, betaq, Wq2, bq2, Wv1, bv1, gv, betav, Wv2, bv2);
}